// Round 4
// baseline (528.276 us; speedup 1.0000x reference)
//
#include <hip/hip_runtime.h>
#include <stdint.h>

#define N_NODES 100000
#define N_EDGES 800000
#define HIDDIM 512
#define HEADS 8
#define FDIM 64

typedef __attribute__((ext_vector_type(4))) float f32x4;
typedef __attribute__((ext_vector_type(8))) short short8;
typedef __attribute__((ext_vector_type(8))) unsigned short ushort8;

// ---- workspace layout (bytes); total need = 113,211,408 ----
static constexpr size_t OFF_PROJ   = 0;            // N*512*2   = 102,400,000 (bf16 proj)
static constexpr size_t OFF_SSRC   = 102400000;    // N*8*4     = 3,200,000
static constexpr size_t OFF_STGT   = 105600000;    // N*8*4
static constexpr size_t OFF_COUNTS = 108800000;    // N*4
static constexpr size_t OFF_ROWOFF = 109200000;    // N*4
static constexpr size_t OFF_CURSOR = 109600000;    // N*4
static constexpr size_t OFF_BSUM   = 110000000;    // 4096
static constexpr size_t OFF_BMAXS  = 110004096;    // 2048
static constexpr size_t OFF_BMAXT  = 110006144;    // 2048
static constexpr size_t OFF_M      = 110008192;    // 16
static constexpr size_t OFF_SSORT  = 110008208;    // E*4 = 3,200,000 (edge srcs in CSR order)
static constexpr size_t ZERO_BYTES = OFF_BSUM - OFF_SSRC;  // zero s_src..cursor

__device__ __forceinline__ unsigned short f2bf(float f) {
  unsigned int u = __builtin_bit_cast(unsigned int, f);
  u += 0x7FFFu + ((u >> 16) & 1u);
  return (unsigned short)(u >> 16);
}
__device__ __forceinline__ float bf2f(unsigned short s) {
  unsigned int u = ((unsigned int)s) << 16;
  return __builtin_bit_cast(float, u);
}

// ---------------- K1: GEMM proj = X @ W^T (+b_lin), fused score dots ----------------
// 128x256 tile, BK=64, 8 waves (2x4), 16x16x32 bf16 MFMA. grid.y=2 -> X read only 2x.
__global__ __launch_bounds__(512) void gemm_proj(
    const float* __restrict__ X, const float* __restrict__ W,
    const float* __restrict__ b_lin, const float* __restrict__ a_src,
    const float* __restrict__ a_tgt,
    unsigned short* __restrict__ proj, float* __restrict__ s_src,
    float* __restrict__ s_tgt) {
  __shared__ __align__(16) unsigned short Al[128 * 64];
  __shared__ __align__(16) unsigned short Bl[256 * 64];
  const int t = threadIdx.x;
  const int bm = blockIdx.x, bn = blockIdx.y;
  const int lane = t & 63, wid = t >> 6;
  const int wr = wid >> 2, wc = wid & 3;  // 2x4 wave grid

  f32x4 acc[4][4] = {};

  for (int kt = 0; kt < 8; ++kt) {
#pragma unroll
    for (int i = 0; i < 4; ++i) {  // stage A: 128x64 f32 -> bf16
      int idx4 = i * 512 + t;
      int row = idx4 >> 4, c4 = (idx4 & 15) * 4;
      int grow = bm * 128 + row;
      if (grow >= N_NODES) grow = N_NODES - 1;
      const float4 v = *(const float4*)&X[(size_t)grow * 512 + kt * 64 + c4];
      ushort4 u;
      u.x = f2bf(v.x); u.y = f2bf(v.y); u.z = f2bf(v.z); u.w = f2bf(v.w);
      *(ushort4*)&Al[row * 64 + c4] = u;
    }
#pragma unroll
    for (int i = 0; i < 8; ++i) {  // stage B: 256 W rows (n,k layout == B^T)
      int idx4 = i * 512 + t;
      int row = idx4 >> 4, c4 = (idx4 & 15) * 4;
      int n = bn * 256 + row;
      const float4 v = *(const float4*)&W[(size_t)n * 512 + kt * 64 + c4];
      ushort4 u;
      u.x = f2bf(v.x); u.y = f2bf(v.y); u.z = f2bf(v.z); u.w = f2bf(v.w);
      *(ushort4*)&Bl[row * 64 + c4] = u;
    }
    __syncthreads();
#pragma unroll
    for (int kk = 0; kk < 2; ++kk) {
      const int kb = kk * 32 + (lane >> 4) * 8;
      short8 af[4], bfr[4];
#pragma unroll
      for (int i = 0; i < 4; ++i)
        af[i] = *(const short8*)&Al[(wr * 64 + i * 16 + (lane & 15)) * 64 + kb];
#pragma unroll
      for (int j = 0; j < 4; ++j)
        bfr[j] = *(const short8*)&Bl[(wc * 64 + j * 16 + (lane & 15)) * 64 + kb];
#pragma unroll
      for (int i = 0; i < 4; ++i)
#pragma unroll
        for (int j = 0; j < 4; ++j)
          acc[i][j] = __builtin_amdgcn_mfma_f32_16x16x32_bf16(af[i], bfr[j], acc[i][j], 0, 0, 0);
    }
    __syncthreads();
  }

  // epilogue: add b_lin, store bf16 proj, fused per-head score dots
  const int col_head_base = bn * 256 + wc * 64;  // wave covers exactly one head
  const int h = col_head_base >> 6;
  float asr[4], atg[4], bl[4];
#pragma unroll
  for (int j = 0; j < 4; ++j) {
    int f = j * 16 + (lane & 15);
    asr[j] = a_src[h * FDIM + f];
    atg[j] = a_tgt[h * FDIM + f];
    bl[j] = b_lin[col_head_base + f];
  }
#pragma unroll
  for (int i = 0; i < 4; ++i) {
#pragma unroll
    for (int r = 0; r < 4; ++r) {
      int grow = bm * 128 + wr * 64 + i * 16 + (lane >> 4) * 4 + r;
      float v[4];
      float ps = 0.f, pt = 0.f;
#pragma unroll
      for (int j = 0; j < 4; ++j) {
        v[j] = acc[i][j][r] + bl[j];
        ps += v[j] * asr[j];
        pt += v[j] * atg[j];
      }
#pragma unroll
      for (int m = 1; m < 16; m <<= 1) {  // reduce over the 16 col-lanes
        ps += __shfl_xor(ps, m);
        pt += __shfl_xor(pt, m);
      }
      if (grow < N_NODES) {
#pragma unroll
        for (int j = 0; j < 4; ++j)
          proj[(size_t)grow * 512 + col_head_base + j * 16 + (lane & 15)] = f2bf(v[j]);
        if ((lane & 15) == 0) {  // exactly one writer per (node, head) -> plain store
          s_src[grow * HEADS + h] = ps;
          s_tgt[grow * HEADS + h] = pt;
        }
      }
    }
  }
}

// ---------------- K1b/K1c: global max of scores -> M ----------------
__global__ void maxred1(const float* __restrict__ s_src, const float* __restrict__ s_tgt,
                        float* __restrict__ bmax_s, float* __restrict__ bmax_t) {
  int t = threadIdx.x;
  float ms = -1e30f, mt = -1e30f;
  for (int i = blockIdx.x * 256 + t; i < N_NODES * HEADS; i += 512 * 256) {
    ms = fmaxf(ms, s_src[i]);
    mt = fmaxf(mt, s_tgt[i]);
  }
#pragma unroll
  for (int m = 1; m < 64; m <<= 1) {
    ms = fmaxf(ms, __shfl_xor(ms, m));
    mt = fmaxf(mt, __shfl_xor(mt, m));
  }
  __shared__ float shs[4], sht[4];
  if ((t & 63) == 0) { shs[t >> 6] = ms; sht[t >> 6] = mt; }
  __syncthreads();
  if (t == 0) {
    ms = fmaxf(fmaxf(shs[0], shs[1]), fmaxf(shs[2], shs[3]));
    mt = fmaxf(fmaxf(sht[0], sht[1]), fmaxf(sht[2], sht[3]));
    bmax_s[blockIdx.x] = ms;
    bmax_t[blockIdx.x] = mt;
  }
}
__global__ void maxred2(const float* __restrict__ bmax_s, const float* __restrict__ bmax_t,
                        float* __restrict__ M) {
  int t = threadIdx.x;
  float ms = bmax_s[t], mt = bmax_t[t];
#pragma unroll
  for (int m = 1; m < 64; m <<= 1) {
    ms = fmaxf(ms, __shfl_xor(ms, m));
    mt = fmaxf(mt, __shfl_xor(mt, m));
  }
  __shared__ float shs[8], sht[8];
  if ((t & 63) == 0) { shs[t >> 6] = ms; sht[t >> 6] = mt; }
  __syncthreads();
  if (t == 0) {
    for (int i = 1; i < 8; ++i) { ms = fmaxf(ms, shs[i]); mt = fmaxf(mt, sht[i]); }
    M[0] = fmaxf(0.0f, ms + mt);  // upper bound on any leaky_relu(edge score); cancels in softmax
  }
}

// ---------------- K2: degree histogram ----------------
__global__ void edge_hist(const int* __restrict__ ei, int* __restrict__ counts) {
  int e = blockIdx.x * 256 + threadIdx.x;
  if (e >= N_EDGES) return;
  atomicAdd(&counts[ei[N_EDGES + e]], 1);
}

// ---------------- K3: exclusive scan of counts -> row_off ----------------
__global__ void scan1(const int* __restrict__ counts, int* __restrict__ row_off,
                      int* __restrict__ bsum) {
  __shared__ int sh[256];
  int t = threadIdx.x, i = blockIdx.x * 256 + t;
  int v = (i < N_NODES) ? counts[i] : 0;
  sh[t] = v;
  __syncthreads();
  for (int off = 1; off < 256; off <<= 1) {
    int x = (t >= off) ? sh[t - off] : 0;
    __syncthreads();
    sh[t] += x;
    __syncthreads();
  }
  if (i < N_NODES) row_off[i] = sh[t] - v;
  if (t == 255) bsum[blockIdx.x] = sh[255];
}
__global__ void scan2(int* __restrict__ bsum, int nb) {
  __shared__ int sh[512];
  int t = threadIdx.x;
  int v = (t < nb) ? bsum[t] : 0;
  sh[t] = v;
  __syncthreads();
  for (int off = 1; off < 512; off <<= 1) {
    int x = (t >= off) ? sh[t - off] : 0;
    __syncthreads();
    sh[t] += x;
    __syncthreads();
  }
  if (t < nb) bsum[t] = sh[t] - v;
}
__global__ void scan3(int* __restrict__ row_off, const int* __restrict__ bsum) {
  int i = blockIdx.x * 256 + threadIdx.x;
  if (i < N_NODES) row_off[i] += bsum[blockIdx.x];
}

// ---------------- K4: scatter edge srcs into CSR order ----------------
__global__ void edge_pass2(const int* __restrict__ ei, const int* __restrict__ row_off,
                           int* __restrict__ cursor, int* __restrict__ sorted_src) {
  int e = blockIdx.x * 256 + threadIdx.x;
  if (e >= N_EDGES) return;
  int src = ei[e], trg = ei[N_EDGES + e];
  int pos = row_off[trg] + atomicAdd(&cursor[trg], 1);
  sorted_src[pos] = src;
}

// ---------------- K5: single-pass softmax-weighted aggregation + bias + PReLU ----------------
// One wave per node (4 waves/block). lane -> (head = lane>>3, 8 features).
// out = (sum_j e_j * proj_j) / (sum_j e_j + 1e-16); identical algebra to reference.
__global__ __launch_bounds__(256) void aggregate(
    const int* __restrict__ row_off, const int* __restrict__ counts,
    const int* __restrict__ sorted_src, const float* __restrict__ s_src,
    const float* __restrict__ s_tgt, const float* __restrict__ Mp,
    const unsigned short* __restrict__ proj,
    const float* __restrict__ bias, const float* __restrict__ prelu_a,
    float* __restrict__ out) {
  const int node = blockIdx.x * 4 + (threadIdx.x >> 6);
  if (node >= N_NODES) return;
  const int lane = threadIdx.x & 63;
  const int h = lane >> 3;        // 8 lanes per head
  const int f8 = (lane & 7) * 8;  // 8 consecutive features per lane
  const int start = row_off[node], deg = counts[node];
  const float st = s_tgt[node * HEADS + h];
  const float M = Mp[0];

  float acc[8] = {};
  float dsum = 0.f;
  for (int j = 0; j < deg; ++j) {
    int s = sorted_src[start + j];
    float x = s_src[s * HEADS + h] + st;
    float l = x > 0.f ? x : 0.01f * x;
    float e = __expf(l - M);
    dsum += e;
    ushort8 pv = *(const ushort8*)&proj[(size_t)s * 512 + h * 64 + f8];
#pragma unroll
    for (int k = 0; k < 8; ++k) acc[k] += e * bf2f(pv[k]);
  }
  const float inv = 1.0f / (dsum + 1e-16f);  // deg==0 -> acc==0 -> out=bias (matches ref)
  const float pa = prelu_a[0];
  const int c = h * 64 + f8;
  float o[8];
#pragma unroll
  for (int k = 0; k < 8; ++k) {
    float v = acc[k] * inv + bias[c + k];
    o[k] = v >= 0.f ? v : pa * v;
  }
  float4* op = (float4*)&out[(size_t)node * 512 + c];
  op[0] = make_float4(o[0], o[1], o[2], o[3]);
  op[1] = make_float4(o[4], o[5], o[6], o[7]);
}

extern "C" void kernel_launch(void* const* d_in, const int* in_sizes, int n_in,
                              void* d_out, int out_size, void* d_ws, size_t ws_size,
                              hipStream_t stream) {
  const float* X = (const float*)d_in[0];
  const int* ei = (const int*)d_in[1];  // harness passes integer inputs as int32
  const float* W = (const float*)d_in[2];
  const float* b_lin = (const float*)d_in[3];
  const float* a_src = (const float*)d_in[4];
  const float* a_tgt = (const float*)d_in[5];
  const float* bias = (const float*)d_in[6];
  const float* prelu_a = (const float*)d_in[7];

  char* ws = (char*)d_ws;
  unsigned short* proj = (unsigned short*)(ws + OFF_PROJ);
  float* s_src = (float*)(ws + OFF_SSRC);
  float* s_tgt = (float*)(ws + OFF_STGT);
  int* counts = (int*)(ws + OFF_COUNTS);
  int* row_off = (int*)(ws + OFF_ROWOFF);
  int* cursor = (int*)(ws + OFF_CURSOR);
  int* bsum = (int*)(ws + OFF_BSUM);
  float* bmax_s = (float*)(ws + OFF_BMAXS);
  float* bmax_t = (float*)(ws + OFF_BMAXT);
  float* Mp = (float*)(ws + OFF_M);
  int* sorted_src = (int*)(ws + OFF_SSORT);

  hipMemsetAsync(ws + OFF_SSRC, 0, ZERO_BYTES, stream);

  gemm_proj<<<dim3(782, 2), 512, 0, stream>>>(X, W, b_lin, a_src, a_tgt, proj, s_src, s_tgt);
  maxred1<<<512, 256, 0, stream>>>(s_src, s_tgt, bmax_s, bmax_t);
  maxred2<<<1, 512, 0, stream>>>(bmax_s, bmax_t, Mp);
  edge_hist<<<3125, 256, 0, stream>>>(ei, counts);
  scan1<<<391, 256, 0, stream>>>(counts, row_off, bsum);
  scan2<<<1, 512, 0, stream>>>(bsum, 391);
  scan3<<<391, 256, 0, stream>>>(row_off, bsum);
  edge_pass2<<<3125, 256, 0, stream>>>(ei, row_off, cursor, sorted_src);
  aggregate<<<25000, 256, 0, stream>>>(row_off, counts, sorted_src, s_src, s_tgt, Mp,
                                       proj, bias, prelu_a, (float*)d_out);
}

// Round 5
// 393.851 us; speedup vs baseline: 1.3413x; 1.3413x over previous
//
#include <hip/hip_runtime.h>
#include <stdint.h>

#define N_NODES 100000
#define N_EDGES 800000
#define HIDDIM 512
#define HEADS 8
#define FDIM 64

typedef __attribute__((ext_vector_type(4))) float f32x4;
typedef __attribute__((ext_vector_type(8))) short short8;
typedef __attribute__((ext_vector_type(8))) unsigned short ushort8;

// ---- workspace layout (bytes); total need = 113,732,496 ----
static constexpr size_t OFF_PROJ   = 0;            // N*512*2   = 102,400,000 (bf16 proj)
static constexpr size_t OFF_SSRC   = 102400000;    // N*8*4     = 3,200,000
static constexpr size_t OFF_STGT   = 105600000;    // N*8*4
static constexpr size_t OFF_COUNTS = 108800000;    // N*4
static constexpr size_t OFF_CURSOR = 109200000;    // N*4   (adjacent to counts -> one memset)
static constexpr size_t OFF_ROWOFF = 109600000;    // N*4
static constexpr size_t OFF_BSUM   = 110000000;    // 4096
static constexpr size_t OFF_BMAXS  = 110004096;    // 2048
static constexpr size_t OFF_BMAXT  = 110006144;    // 2048
static constexpr size_t OFF_M      = 110008192;    // 16
static constexpr size_t OFF_SSORT  = 110008208;    // E*4 = 3,200,000 (edge srcs in CSR order)
static constexpr size_t OFF_WB     = 113208208;    // 512*512*2 = 524,288 (bf16 W)
static constexpr size_t ZERO_BYTES = 800000;       // counts + cursor

__device__ __forceinline__ unsigned short f2bf(float f) {
  unsigned int u = __builtin_bit_cast(unsigned int, f);
  u += 0x7FFFu + ((u >> 16) & 1u);
  return (unsigned short)(u >> 16);
}
__device__ __forceinline__ float bf2f(unsigned short s) {
  unsigned int u = ((unsigned int)s) << 16;
  return __builtin_bit_cast(float, u);
}
__device__ __forceinline__ void gload_lds16(const void* g, void* l) {
  __builtin_amdgcn_global_load_lds((const __attribute__((address_space(1))) unsigned int*)g,
                                   (__attribute__((address_space(3))) unsigned int*)l, 16, 0, 0);
}

// ---------------- K0: convert W (512x512 f32) -> bf16 ----------------
__global__ __launch_bounds__(256) void convert_w(const float* __restrict__ W,
                                                 unsigned short* __restrict__ Wb) {
  int i = blockIdx.x * 256 + threadIdx.x;  // 32768 threads x 8 elems = 262144
  const float4 v0 = *(const float4*)&W[(size_t)i * 8];
  const float4 v1 = *(const float4*)&W[(size_t)i * 8 + 4];
  ushort8 u;
  u[0] = f2bf(v0.x); u[1] = f2bf(v0.y); u[2] = f2bf(v0.z); u[3] = f2bf(v0.w);
  u[4] = f2bf(v1.x); u[5] = f2bf(v1.y); u[6] = f2bf(v1.z); u[7] = f2bf(v1.w);
  *(ushort8*)&Wb[(size_t)i * 8] = u;
}

// ---------------- K1: GEMM proj = X @ W^T (+b_lin), fused score dots ----------------
// 128x256 tile, BK=64, 8 waves (2x4). B staged via global_load_lds (pre-swizzled
// global source, rule #21); A reg-staged f32->bf16 with swizzled ds_write_b128.
// LDS tiles use chunk ^= (row&7) swizzle (16B chunks) -> bank-conflict-free reads.
__global__ __launch_bounds__(512) void gemm_proj(
    const float* __restrict__ X, const unsigned short* __restrict__ Wb,
    const float* __restrict__ b_lin, const float* __restrict__ a_src,
    const float* __restrict__ a_tgt,
    unsigned short* __restrict__ proj, float* __restrict__ s_src,
    float* __restrict__ s_tgt) {
  __shared__ __align__(16) unsigned short Al[128 * 64];
  __shared__ __align__(16) unsigned short Bl[256 * 64];
  const int t = threadIdx.x;
  const int bm = blockIdx.x, bn = blockIdx.y;
  const int lane = t & 63, wid = t >> 6;
  const int wr = wid >> 2, wc = wid & 3;  // 2x4 wave grid

  f32x4 acc[4][4] = {};

  // B staging: wave-load ci = wid*4+i covers Bl rows ci*8..ci*8+7 (1 KB linear).
  // Lane l lands at LDS (row = ci*8 + (l>>3), chunk = l&7); fetch global chunk
  // (l&7)^(l>>3) so that LDS[row][c] = global chunk c^(row&7).
  const int brow0 = bn * 256 + wid * 32 + (lane >> 3);
  const int bsrc_c = ((lane & 7) ^ (lane >> 3)) * 8;  // bf16 elems

  for (int kt = 0; kt < 8; ++kt) {
#pragma unroll
    for (int i = 0; i < 4; ++i)
      gload_lds16(&Wb[(size_t)(brow0 + i * 8) * 512 + kt * 64 + bsrc_c],
                  &Bl[(wid * 4 + i) * 512]);
#pragma unroll
    for (int i = 0; i < 2; ++i) {  // A: 128x64, 8 elems/thread/iter
      int idx8 = i * 512 + t;
      int row = idx8 >> 3, ck = idx8 & 7;
      int grow = bm * 128 + row;
      if (grow >= N_NODES) grow = N_NODES - 1;
      const float4 v0 = *(const float4*)&X[(size_t)grow * 512 + kt * 64 + ck * 8];
      const float4 v1 = *(const float4*)&X[(size_t)grow * 512 + kt * 64 + ck * 8 + 4];
      ushort8 u;
      u[0] = f2bf(v0.x); u[1] = f2bf(v0.y); u[2] = f2bf(v0.z); u[3] = f2bf(v0.w);
      u[4] = f2bf(v1.x); u[5] = f2bf(v1.y); u[6] = f2bf(v1.z); u[7] = f2bf(v1.w);
      *(ushort8*)&Al[row * 64 + ((ck ^ (row & 7)) * 8)] = u;
    }
    __syncthreads();
#pragma unroll
    for (int kk = 0; kk < 2; ++kk) {
      short8 af[4], bfr[4];
#pragma unroll
      for (int i = 0; i < 4; ++i) {
        int row = wr * 64 + i * 16 + (lane & 15);
        int ck = (kk * 4 + (lane >> 4)) ^ (row & 7);
        af[i] = *(const short8*)&Al[row * 64 + ck * 8];
      }
#pragma unroll
      for (int j = 0; j < 4; ++j) {
        int row = wc * 64 + j * 16 + (lane & 15);
        int ck = (kk * 4 + (lane >> 4)) ^ (row & 7);
        bfr[j] = *(const short8*)&Bl[row * 64 + ck * 8];
      }
#pragma unroll
      for (int i = 0; i < 4; ++i)
#pragma unroll
        for (int j = 0; j < 4; ++j)
          acc[i][j] = __builtin_amdgcn_mfma_f32_16x16x32_bf16(af[i], bfr[j], acc[i][j], 0, 0, 0);
    }
    __syncthreads();
  }

  // epilogue: add b_lin, store bf16 proj, fused per-head score dots
  const int col_head_base = bn * 256 + wc * 64;  // wave covers exactly one head
  const int h = col_head_base >> 6;
  float asr[4], atg[4], bl[4];
#pragma unroll
  for (int j = 0; j < 4; ++j) {
    int f = j * 16 + (lane & 15);
    asr[j] = a_src[h * FDIM + f];
    atg[j] = a_tgt[h * FDIM + f];
    bl[j] = b_lin[col_head_base + f];
  }
#pragma unroll
  for (int i = 0; i < 4; ++i) {
#pragma unroll
    for (int r = 0; r < 4; ++r) {
      int grow = bm * 128 + wr * 64 + i * 16 + (lane >> 4) * 4 + r;
      float v[4];
      float ps = 0.f, pt = 0.f;
#pragma unroll
      for (int j = 0; j < 4; ++j) {
        v[j] = acc[i][j][r] + bl[j];
        ps += v[j] * asr[j];
        pt += v[j] * atg[j];
      }
#pragma unroll
      for (int m = 1; m < 16; m <<= 1) {  // reduce over the 16 col-lanes
        ps += __shfl_xor(ps, m);
        pt += __shfl_xor(pt, m);
      }
      if (grow < N_NODES) {
#pragma unroll
        for (int j = 0; j < 4; ++j)
          proj[(size_t)grow * 512 + col_head_base + j * 16 + (lane & 15)] = f2bf(v[j]);
        if ((lane & 15) == 0) {  // exactly one writer per (node, head) -> plain store
          s_src[grow * HEADS + h] = ps;
          s_tgt[grow * HEADS + h] = pt;
        }
      }
    }
  }
}

// ---------------- K1b/K1c: global max of scores -> M ----------------
__global__ void maxred1(const float* __restrict__ s_src, const float* __restrict__ s_tgt,
                        float* __restrict__ bmax_s, float* __restrict__ bmax_t) {
  int t = threadIdx.x;
  float ms = -1e30f, mt = -1e30f;
  for (int i = blockIdx.x * 256 + t; i < N_NODES * HEADS; i += 512 * 256) {
    ms = fmaxf(ms, s_src[i]);
    mt = fmaxf(mt, s_tgt[i]);
  }
#pragma unroll
  for (int m = 1; m < 64; m <<= 1) {
    ms = fmaxf(ms, __shfl_xor(ms, m));
    mt = fmaxf(mt, __shfl_xor(mt, m));
  }
  __shared__ float shs[4], sht[4];
  if ((t & 63) == 0) { shs[t >> 6] = ms; sht[t >> 6] = mt; }
  __syncthreads();
  if (t == 0) {
    ms = fmaxf(fmaxf(shs[0], shs[1]), fmaxf(shs[2], shs[3]));
    mt = fmaxf(fmaxf(sht[0], sht[1]), fmaxf(sht[2], sht[3]));
    bmax_s[blockIdx.x] = ms;
    bmax_t[blockIdx.x] = mt;
  }
}
__global__ void maxred2(const float* __restrict__ bmax_s, const float* __restrict__ bmax_t,
                        float* __restrict__ M) {
  int t = threadIdx.x;
  float ms = bmax_s[t], mt = bmax_t[t];
#pragma unroll
  for (int m = 1; m < 64; m <<= 1) {
    ms = fmaxf(ms, __shfl_xor(ms, m));
    mt = fmaxf(mt, __shfl_xor(mt, m));
  }
  __shared__ float shs[8], sht[8];
  if ((t & 63) == 0) { shs[t >> 6] = ms; sht[t >> 6] = mt; }
  __syncthreads();
  if (t == 0) {
    for (int i = 1; i < 8; ++i) { ms = fmaxf(ms, shs[i]); mt = fmaxf(mt, sht[i]); }
    M[0] = fmaxf(0.0f, ms + mt);  // upper bound on any leaky_relu(edge score); cancels in softmax
  }
}

// ---------------- K2: degree histogram ----------------
__global__ void edge_hist(const int* __restrict__ ei, int* __restrict__ counts) {
  int e = blockIdx.x * 256 + threadIdx.x;
  if (e >= N_EDGES) return;
  atomicAdd(&counts[ei[N_EDGES + e]], 1);
}

// ---------------- K3: exclusive scan of counts -> row_off ----------------
__global__ void scan1(const int* __restrict__ counts, int* __restrict__ row_off,
                      int* __restrict__ bsum) {
  __shared__ int sh[256];
  int t = threadIdx.x, i = blockIdx.x * 256 + t;
  int v = (i < N_NODES) ? counts[i] : 0;
  sh[t] = v;
  __syncthreads();
  for (int off = 1; off < 256; off <<= 1) {
    int x = (t >= off) ? sh[t - off] : 0;
    __syncthreads();
    sh[t] += x;
    __syncthreads();
  }
  if (i < N_NODES) row_off[i] = sh[t] - v;
  if (t == 255) bsum[blockIdx.x] = sh[255];
}
__global__ void scan2(int* __restrict__ bsum, int nb) {
  __shared__ int sh[512];
  int t = threadIdx.x;
  int v = (t < nb) ? bsum[t] : 0;
  sh[t] = v;
  __syncthreads();
  for (int off = 1; off < 512; off <<= 1) {
    int x = (t >= off) ? sh[t - off] : 0;
    __syncthreads();
    sh[t] += x;
    __syncthreads();
  }
  if (t < nb) bsum[t] = sh[t] - v;
}
__global__ void scan3(int* __restrict__ row_off, const int* __restrict__ bsum) {
  int i = blockIdx.x * 256 + threadIdx.x;
  if (i < N_NODES) row_off[i] += bsum[blockIdx.x];
}

// ---------------- K4: scatter edge srcs into CSR order ----------------
__global__ void edge_pass2(const int* __restrict__ ei, const int* __restrict__ row_off,
                           int* __restrict__ cursor, int* __restrict__ sorted_src) {
  int e = blockIdx.x * 256 + threadIdx.x;
  if (e >= N_EDGES) return;
  int src = ei[e], trg = ei[N_EDGES + e];
  int pos = row_off[trg] + atomicAdd(&cursor[trg], 1);
  sorted_src[pos] = src;
}

// ---------------- K5: single-pass softmax-weighted aggregation + bias + PReLU ----------------
// One wave per node (4 waves/block). lane -> (head = lane>>3, 8 features).
// out = (sum_j e_j * proj_j) / (sum_j e_j + 1e-16); identical algebra to reference.
__global__ __launch_bounds__(256) void aggregate(
    const int* __restrict__ row_off, const int* __restrict__ counts,
    const int* __restrict__ sorted_src, const float* __restrict__ s_src,
    const float* __restrict__ s_tgt, const float* __restrict__ Mp,
    const unsigned short* __restrict__ proj,
    const float* __restrict__ bias, const float* __restrict__ prelu_a,
    float* __restrict__ out) {
  const int node = blockIdx.x * 4 + (threadIdx.x >> 6);
  if (node >= N_NODES) return;
  const int lane = threadIdx.x & 63;
  const int h = lane >> 3;        // 8 lanes per head
  const int f8 = (lane & 7) * 8;  // 8 consecutive features per lane
  const int start = row_off[node], deg = counts[node];
  const float st = s_tgt[node * HEADS + h];
  const float M = Mp[0];

  float acc[8] = {};
  float dsum = 0.f;
  for (int j = 0; j < deg; ++j) {
    int s = sorted_src[start + j];
    float x = s_src[s * HEADS + h] + st;
    float l = x > 0.f ? x : 0.01f * x;
    float e = __expf(l - M);
    dsum += e;
    ushort8 pv = *(const ushort8*)&proj[(size_t)s * 512 + h * 64 + f8];
#pragma unroll
    for (int k = 0; k < 8; ++k) acc[k] += e * bf2f(pv[k]);
  }
  const float inv = 1.0f / (dsum + 1e-16f);  // deg==0 -> acc==0 -> out=bias (matches ref)
  const float pa = prelu_a[0];
  const int c = h * 64 + f8;
  float o[8];
#pragma unroll
  for (int k = 0; k < 8; ++k) {
    float v = acc[k] * inv + bias[c + k];
    o[k] = v >= 0.f ? v : pa * v;
  }
  float4* op = (float4*)&out[(size_t)node * 512 + c];
  op[0] = make_float4(o[0], o[1], o[2], o[3]);
  op[1] = make_float4(o[4], o[5], o[6], o[7]);
}

extern "C" void kernel_launch(void* const* d_in, const int* in_sizes, int n_in,
                              void* d_out, int out_size, void* d_ws, size_t ws_size,
                              hipStream_t stream) {
  const float* X = (const float*)d_in[0];
  const int* ei = (const int*)d_in[1];  // harness passes integer inputs as int32
  const float* W = (const float*)d_in[2];
  const float* b_lin = (const float*)d_in[3];
  const float* a_src = (const float*)d_in[4];
  const float* a_tgt = (const float*)d_in[5];
  const float* bias = (const float*)d_in[6];
  const float* prelu_a = (const float*)d_in[7];

  char* ws = (char*)d_ws;
  unsigned short* proj = (unsigned short*)(ws + OFF_PROJ);
  float* s_src = (float*)(ws + OFF_SSRC);
  float* s_tgt = (float*)(ws + OFF_STGT);
  int* counts = (int*)(ws + OFF_COUNTS);
  int* cursor = (int*)(ws + OFF_CURSOR);
  int* row_off = (int*)(ws + OFF_ROWOFF);
  int* bsum = (int*)(ws + OFF_BSUM);
  float* bmax_s = (float*)(ws + OFF_BMAXS);
  float* bmax_t = (float*)(ws + OFF_BMAXT);
  float* Mp = (float*)(ws + OFF_M);
  int* sorted_src = (int*)(ws + OFF_SSORT);
  unsigned short* Wb = (unsigned short*)(ws + OFF_WB);

  hipMemsetAsync(ws + OFF_COUNTS, 0, ZERO_BYTES, stream);

  convert_w<<<128, 256, 0, stream>>>(W, Wb);
  gemm_proj<<<dim3(782, 2), 512, 0, stream>>>(X, Wb, b_lin, a_src, a_tgt, proj, s_src, s_tgt);
  maxred1<<<512, 256, 0, stream>>>(s_src, s_tgt, bmax_s, bmax_t);
  maxred2<<<1, 512, 0, stream>>>(bmax_s, bmax_t, Mp);
  edge_hist<<<3125, 256, 0, stream>>>(ei, counts);
  scan1<<<391, 256, 0, stream>>>(counts, row_off, bsum);
  scan2<<<1, 512, 0, stream>>>(bsum, 391);
  scan3<<<391, 256, 0, stream>>>(row_off, bsum);
  edge_pass2<<<3125, 256, 0, stream>>>(ei, row_off, cursor, sorted_src);
  aggregate<<<25000, 256, 0, stream>>>(row_off, counts, sorted_src, s_src, s_tgt, Mp,
                                       proj, bias, prelu_a, (float*)d_out);
}

// Round 6
// 388.925 us; speedup vs baseline: 1.3583x; 1.0127x over previous
//
#include <hip/hip_runtime.h>
#include <stdint.h>

#define N_NODES 100000
#define N_EDGES 800000
#define HIDDIM 512
#define HEADS 8
#define FDIM 64

typedef __attribute__((ext_vector_type(4))) float f32x4;
typedef __attribute__((ext_vector_type(8))) short short8;
typedef __attribute__((ext_vector_type(8))) unsigned short ushort8;

// ---- workspace layout (bytes); total need = 113,732,496 ----
static constexpr size_t OFF_PROJ   = 0;            // N*512*2   = 102,400,000 (bf16 proj)
static constexpr size_t OFF_SSRC   = 102400000;    // N*8*4     = 3,200,000
static constexpr size_t OFF_STGT   = 105600000;    // N*8*4
static constexpr size_t OFF_COUNTS = 108800000;    // N*4
static constexpr size_t OFF_CURSOR = 109200000;    // N*4   (adjacent to counts -> one memset)
static constexpr size_t OFF_ROWOFF = 109600000;    // N*4
static constexpr size_t OFF_BSUM   = 110000000;    // 4096
static constexpr size_t OFF_BMAXS  = 110004096;    // 2048
static constexpr size_t OFF_BMAXT  = 110006144;    // 2048
static constexpr size_t OFF_M      = 110008192;    // 16
static constexpr size_t OFF_SSORT  = 110008208;    // E*4 = 3,200,000 (edge srcs in CSR order)
static constexpr size_t OFF_WB     = 113208208;    // 512*512*2 = 524,288 (bf16 W)
static constexpr size_t ZERO_BYTES = 800000;       // counts + cursor

__device__ __forceinline__ unsigned short f2bf(float f) {
  unsigned int u = __builtin_bit_cast(unsigned int, f);
  u += 0x7FFFu + ((u >> 16) & 1u);
  return (unsigned short)(u >> 16);
}
__device__ __forceinline__ float bf2f(unsigned short s) {
  unsigned int u = ((unsigned int)s) << 16;
  return __builtin_bit_cast(float, u);
}
__device__ __forceinline__ void gload_lds16(const void* g, void* l) {
  __builtin_amdgcn_global_load_lds((const __attribute__((address_space(1))) unsigned int*)g,
                                   (__attribute__((address_space(3))) unsigned int*)l, 16, 0, 0);
}

// ---------------- K0: convert W (512x512 f32) -> bf16 ----------------
__global__ __launch_bounds__(256) void convert_w(const float* __restrict__ W,
                                                 unsigned short* __restrict__ Wb) {
  int i = blockIdx.x * 256 + threadIdx.x;  // 32768 threads x 8 elems = 262144
  const float4 v0 = *(const float4*)&W[(size_t)i * 8];
  const float4 v1 = *(const float4*)&W[(size_t)i * 8 + 4];
  ushort8 u;
  u[0] = f2bf(v0.x); u[1] = f2bf(v0.y); u[2] = f2bf(v0.z); u[3] = f2bf(v0.w);
  u[4] = f2bf(v1.x); u[5] = f2bf(v1.y); u[6] = f2bf(v1.z); u[7] = f2bf(v1.w);
  *(ushort8*)&Wb[(size_t)i * 8] = u;
}

// ---------------- K1: GEMM proj = X @ W^T (+b_lin), fused score dots ----------------
// 128x256 tile, BK=64, 8 waves (2x4). B staged via global_load_lds (pre-swizzled
// global source, rule #21); A reg-staged f32->bf16 with swizzled ds_write_b128.
// LDS tiles use chunk ^= (row&7) swizzle (16B chunks) -> bank-conflict-free reads.
__global__ __launch_bounds__(512) void gemm_proj(
    const float* __restrict__ X, const unsigned short* __restrict__ Wb,
    const float* __restrict__ b_lin, const float* __restrict__ a_src,
    const float* __restrict__ a_tgt,
    unsigned short* __restrict__ proj, float* __restrict__ s_src,
    float* __restrict__ s_tgt) {
  __shared__ __align__(16) unsigned short Al[128 * 64];
  __shared__ __align__(16) unsigned short Bl[256 * 64];
  const int t = threadIdx.x;
  const int bm = blockIdx.x, bn = blockIdx.y;
  const int lane = t & 63, wid = t >> 6;
  const int wr = wid >> 2, wc = wid & 3;  // 2x4 wave grid

  f32x4 acc[4][4] = {};

  // B staging: wave-load ci = wid*4+i covers Bl rows ci*8..ci*8+7 (1 KB linear).
  // Lane l lands at LDS (row = ci*8 + (l>>3), chunk = l&7); fetch global chunk
  // (l&7)^(l>>3) so that LDS[row][c] = global chunk c^(row&7).
  const int brow0 = bn * 256 + wid * 32 + (lane >> 3);
  const int bsrc_c = ((lane & 7) ^ (lane >> 3)) * 8;  // bf16 elems

  for (int kt = 0; kt < 8; ++kt) {
#pragma unroll
    for (int i = 0; i < 4; ++i)
      gload_lds16(&Wb[(size_t)(brow0 + i * 8) * 512 + kt * 64 + bsrc_c],
                  &Bl[(wid * 4 + i) * 512]);
#pragma unroll
    for (int i = 0; i < 2; ++i) {  // A: 128x64, 8 elems/thread/iter
      int idx8 = i * 512 + t;
      int row = idx8 >> 3, ck = idx8 & 7;
      int grow = bm * 128 + row;
      if (grow >= N_NODES) grow = N_NODES - 1;
      const float4 v0 = *(const float4*)&X[(size_t)grow * 512 + kt * 64 + ck * 8];
      const float4 v1 = *(const float4*)&X[(size_t)grow * 512 + kt * 64 + ck * 8 + 4];
      ushort8 u;
      u[0] = f2bf(v0.x); u[1] = f2bf(v0.y); u[2] = f2bf(v0.z); u[3] = f2bf(v0.w);
      u[4] = f2bf(v1.x); u[5] = f2bf(v1.y); u[6] = f2bf(v1.z); u[7] = f2bf(v1.w);
      *(ushort8*)&Al[row * 64 + ((ck ^ (row & 7)) * 8)] = u;
    }
    __syncthreads();
#pragma unroll
    for (int kk = 0; kk < 2; ++kk) {
      short8 af[4], bfr[4];
#pragma unroll
      for (int i = 0; i < 4; ++i) {
        int row = wr * 64 + i * 16 + (lane & 15);
        int ck = (kk * 4 + (lane >> 4)) ^ (row & 7);
        af[i] = *(const short8*)&Al[row * 64 + ck * 8];
      }
#pragma unroll
      for (int j = 0; j < 4; ++j) {
        int row = wc * 64 + j * 16 + (lane & 15);
        int ck = (kk * 4 + (lane >> 4)) ^ (row & 7);
        bfr[j] = *(const short8*)&Bl[row * 64 + ck * 8];
      }
#pragma unroll
      for (int i = 0; i < 4; ++i)
#pragma unroll
        for (int j = 0; j < 4; ++j)
          acc[i][j] = __builtin_amdgcn_mfma_f32_16x16x32_bf16(af[i], bfr[j], acc[i][j], 0, 0, 0);
    }
    __syncthreads();
  }

  // epilogue: add b_lin, store bf16 proj, fused per-head score dots
  const int col_head_base = bn * 256 + wc * 64;  // wave covers exactly one head
  const int h = col_head_base >> 6;
  float asr[4], atg[4], bl[4];
#pragma unroll
  for (int j = 0; j < 4; ++j) {
    int f = j * 16 + (lane & 15);
    asr[j] = a_src[h * FDIM + f];
    atg[j] = a_tgt[h * FDIM + f];
    bl[j] = b_lin[col_head_base + f];
  }
#pragma unroll
  for (int i = 0; i < 4; ++i) {
#pragma unroll
    for (int r = 0; r < 4; ++r) {
      int grow = bm * 128 + wr * 64 + i * 16 + (lane >> 4) * 4 + r;
      float v[4];
      float ps = 0.f, pt = 0.f;
#pragma unroll
      for (int j = 0; j < 4; ++j) {
        v[j] = acc[i][j][r] + bl[j];
        ps += v[j] * asr[j];
        pt += v[j] * atg[j];
      }
#pragma unroll
      for (int m = 1; m < 16; m <<= 1) {  // reduce over the 16 col-lanes
        ps += __shfl_xor(ps, m);
        pt += __shfl_xor(pt, m);
      }
      if (grow < N_NODES) {
#pragma unroll
        for (int j = 0; j < 4; ++j)
          proj[(size_t)grow * 512 + col_head_base + j * 16 + (lane & 15)] = f2bf(v[j]);
        if ((lane & 15) == 0) {  // exactly one writer per (node, head) -> plain store
          s_src[grow * HEADS + h] = ps;
          s_tgt[grow * HEADS + h] = pt;
        }
      }
    }
  }
}

// ---------------- K1b/K1c: global max of scores -> M ----------------
__global__ void maxred1(const float* __restrict__ s_src, const float* __restrict__ s_tgt,
                        float* __restrict__ bmax_s, float* __restrict__ bmax_t) {
  int t = threadIdx.x;
  float ms = -1e30f, mt = -1e30f;
  for (int i = blockIdx.x * 256 + t; i < N_NODES * HEADS; i += 512 * 256) {
    ms = fmaxf(ms, s_src[i]);
    mt = fmaxf(mt, s_tgt[i]);
  }
#pragma unroll
  for (int m = 1; m < 64; m <<= 1) {
    ms = fmaxf(ms, __shfl_xor(ms, m));
    mt = fmaxf(mt, __shfl_xor(mt, m));
  }
  __shared__ float shs[4], sht[4];
  if ((t & 63) == 0) { shs[t >> 6] = ms; sht[t >> 6] = mt; }
  __syncthreads();
  if (t == 0) {
    ms = fmaxf(fmaxf(shs[0], shs[1]), fmaxf(shs[2], shs[3]));
    mt = fmaxf(fmaxf(sht[0], sht[1]), fmaxf(sht[2], sht[3]));
    bmax_s[blockIdx.x] = ms;
    bmax_t[blockIdx.x] = mt;
  }
}
__global__ void maxred2(const float* __restrict__ bmax_s, const float* __restrict__ bmax_t,
                        float* __restrict__ M) {
  int t = threadIdx.x;
  float ms = bmax_s[t], mt = bmax_t[t];
#pragma unroll
  for (int m = 1; m < 64; m <<= 1) {
    ms = fmaxf(ms, __shfl_xor(ms, m));
    mt = fmaxf(mt, __shfl_xor(mt, m));
  }
  __shared__ float shs[8], sht[8];
  if ((t & 63) == 0) { shs[t >> 6] = ms; sht[t >> 6] = mt; }
  __syncthreads();
  if (t == 0) {
    for (int i = 1; i < 8; ++i) { ms = fmaxf(ms, shs[i]); mt = fmaxf(mt, sht[i]); }
    M[0] = fmaxf(0.0f, ms + mt);  // upper bound on any leaky_relu(edge score); cancels in softmax
  }
}

// ---------------- K2: degree histogram ----------------
__global__ void edge_hist(const int* __restrict__ ei, int* __restrict__ counts) {
  int e = blockIdx.x * 256 + threadIdx.x;
  if (e >= N_EDGES) return;
  atomicAdd(&counts[ei[N_EDGES + e]], 1);
}

// ---------------- K3: exclusive scan of counts -> row_off ----------------
__global__ void scan1(const int* __restrict__ counts, int* __restrict__ row_off,
                      int* __restrict__ bsum) {
  __shared__ int sh[256];
  int t = threadIdx.x, i = blockIdx.x * 256 + t;
  int v = (i < N_NODES) ? counts[i] : 0;
  sh[t] = v;
  __syncthreads();
  for (int off = 1; off < 256; off <<= 1) {
    int x = (t >= off) ? sh[t - off] : 0;
    __syncthreads();
    sh[t] += x;
    __syncthreads();
  }
  if (i < N_NODES) row_off[i] = sh[t] - v;
  if (t == 255) bsum[blockIdx.x] = sh[255];
}
__global__ void scan2(int* __restrict__ bsum, int nb) {
  __shared__ int sh[512];
  int t = threadIdx.x;
  int v = (t < nb) ? bsum[t] : 0;
  sh[t] = v;
  __syncthreads();
  for (int off = 1; off < 512; off <<= 1) {
    int x = (t >= off) ? sh[t - off] : 0;
    __syncthreads();
    sh[t] += x;
    __syncthreads();
  }
  if (t < nb) bsum[t] = sh[t] - v;
}
__global__ void scan3(int* __restrict__ row_off, const int* __restrict__ bsum) {
  int i = blockIdx.x * 256 + threadIdx.x;
  if (i < N_NODES) row_off[i] += bsum[blockIdx.x];
}

// ---------------- K4: scatter edge srcs into CSR order ----------------
__global__ void edge_pass2(const int* __restrict__ ei, const int* __restrict__ row_off,
                           int* __restrict__ cursor, int* __restrict__ sorted_src) {
  int e = blockIdx.x * 256 + threadIdx.x;
  if (e >= N_EDGES) return;
  int src = ei[e], trg = ei[N_EDGES + e];
  int pos = row_off[trg] + atomicAdd(&cursor[trg], 1);
  sorted_src[pos] = src;
}

// ---------------- K5: single-pass softmax-weighted aggregation + bias + PReLU ----------------
// One wave per node (4 waves/block). lane -> (head = lane>>3, 8 features).
// Edges processed in batches of 4: all 4 index loads, then all 4 s_src gathers and
// all 4 proj-row loads issued back-to-back (independent) before accumulation ->
// ~4x memory-level parallelism on the gather chain.
__global__ __launch_bounds__(256) void aggregate(
    const int* __restrict__ row_off, const int* __restrict__ counts,
    const int* __restrict__ sorted_src, const float* __restrict__ s_src,
    const float* __restrict__ s_tgt, const float* __restrict__ Mp,
    const unsigned short* __restrict__ proj,
    const float* __restrict__ bias, const float* __restrict__ prelu_a,
    float* __restrict__ out) {
  const int node = blockIdx.x * 4 + (threadIdx.x >> 6);
  if (node >= N_NODES) return;
  const int lane = threadIdx.x & 63;
  const int h = lane >> 3;        // 8 lanes per head
  const int f8 = (lane & 7) * 8;  // 8 consecutive features per lane
  const int start = row_off[node], deg = counts[node];
  const float st = s_tgt[node * HEADS + h];
  const float M = Mp[0];

  float acc[8] = {};
  float dsum = 0.f;
  for (int jb = 0; jb < deg; jb += 4) {
    const int nb = deg - jb;  // >= 1
    int s[4];
#pragma unroll
    for (int i = 0; i < 4; ++i) s[i] = sorted_src[start + jb + (i < nb ? i : 0)];
    float x[4];
#pragma unroll
    for (int i = 0; i < 4; ++i) x[i] = s_src[s[i] * HEADS + h];
    ushort8 p[4];
#pragma unroll
    for (int i = 0; i < 4; ++i)
      p[i] = *(const ushort8*)&proj[(size_t)s[i] * 512 + h * 64 + f8];
#pragma unroll
    for (int i = 0; i < 4; ++i) {
      if (i < nb) {
        float xx = x[i] + st;
        float l = xx > 0.f ? xx : 0.01f * xx;
        float e = __expf(l - M);
        dsum += e;
#pragma unroll
        for (int k = 0; k < 8; ++k) acc[k] += e * bf2f(p[i][k]);
      }
    }
  }
  const float inv = 1.0f / (dsum + 1e-16f);  // deg==0 -> acc==0 -> out=bias (matches ref)
  const float pa = prelu_a[0];
  const int c = h * 64 + f8;
  float o[8];
#pragma unroll
  for (int k = 0; k < 8; ++k) {
    float v = acc[k] * inv + bias[c + k];
    o[k] = v >= 0.f ? v : pa * v;
  }
  float4* op = (float4*)&out[(size_t)node * 512 + c];
  op[0] = make_float4(o[0], o[1], o[2], o[3]);
  op[1] = make_float4(o[4], o[5], o[6], o[7]);
}

extern "C" void kernel_launch(void* const* d_in, const int* in_sizes, int n_in,
                              void* d_out, int out_size, void* d_ws, size_t ws_size,
                              hipStream_t stream) {
  const float* X = (const float*)d_in[0];
  const int* ei = (const int*)d_in[1];  // harness passes integer inputs as int32
  const float* W = (const float*)d_in[2];
  const float* b_lin = (const float*)d_in[3];
  const float* a_src = (const float*)d_in[4];
  const float* a_tgt = (const float*)d_in[5];
  const float* bias = (const float*)d_in[6];
  const float* prelu_a = (const float*)d_in[7];

  char* ws = (char*)d_ws;
  unsigned short* proj = (unsigned short*)(ws + OFF_PROJ);
  float* s_src = (float*)(ws + OFF_SSRC);
  float* s_tgt = (float*)(ws + OFF_STGT);
  int* counts = (int*)(ws + OFF_COUNTS);
  int* cursor = (int*)(ws + OFF_CURSOR);
  int* row_off = (int*)(ws + OFF_ROWOFF);
  int* bsum = (int*)(ws + OFF_BSUM);
  float* bmax_s = (float*)(ws + OFF_BMAXS);
  float* bmax_t = (float*)(ws + OFF_BMAXT);
  float* Mp = (float*)(ws + OFF_M);
  int* sorted_src = (int*)(ws + OFF_SSORT);
  unsigned short* Wb = (unsigned short*)(ws + OFF_WB);

  hipMemsetAsync(ws + OFF_COUNTS, 0, ZERO_BYTES, stream);

  convert_w<<<128, 256, 0, stream>>>(W, Wb);
  gemm_proj<<<dim3(782, 2), 512, 0, stream>>>(X, Wb, b_lin, a_src, a_tgt, proj, s_src, s_tgt);
  maxred1<<<512, 256, 0, stream>>>(s_src, s_tgt, bmax_s, bmax_t);
  maxred2<<<1, 512, 0, stream>>>(bmax_s, bmax_t, Mp);
  edge_hist<<<3125, 256, 0, stream>>>(ei, counts);
  scan1<<<391, 256, 0, stream>>>(counts, row_off, bsum);
  scan2<<<1, 512, 0, stream>>>(bsum, 391);
  scan3<<<391, 256, 0, stream>>>(row_off, bsum);
  edge_pass2<<<3125, 256, 0, stream>>>(ei, row_off, cursor, sorted_src);
  aggregate<<<25000, 256, 0, stream>>>(row_off, counts, sorted_src, s_src, s_tgt, Mp,
                                       proj, bias, prelu_a, (float*)d_out);
}